// Round 1
// baseline (89.824 us; speedup 1.0000x reference)
//
#include <hip/hip_runtime.h>
#include <math.h>

#define NB 128
#define NC 8
#define NV 16384
#define NK 64
#define NR 128

// flat output offsets (elements, f32)
#define OFF_MASKS  0
#define OFF_VP     2097152
#define OFF_THETAS 8388608
#define OFF_ALPHAS 8388736
#define OFF_ROT    8388864
#define OFF_SCALES 8389376
#define OFF_DEPTHS 8389504
#define OFF_C2D    8389632
#define OFF_TRANS  8389888
#define OFF_CLP    8390272

#define PI_F     3.14159265358979323846f
#define TWOPI_F  6.28318530717958647692f

struct BParams {
  int   cls;
  float scale, qw, qy, tx, ty, tz, feff;
};

// shared math for the per-batch parameters needed by the verts kernel
__device__ __forceinline__ BParams compute_params(
    int b,
    const float* __restrict__ roi, const float* __restrict__ focals,
    const float* __restrict__ td,  const float* __restrict__ t2,
    const float* __restrict__ ls,  const float* __restrict__ ld,
    const float* __restrict__ cp) {
  BParams p;
  float r0 = roi[b * 4 + 0], r1 = roi[b * 4 + 1];
  float r2 = roi[b * 4 + 2], r3 = roi[b * 4 + 3];
  float dx = r2 - r0, dy = r3 - r1;
  float mx = 0.5f * (r2 + r0), my = 0.5f * (r3 + r1);
  float theta = atan2f(td[b * 2 + 1], td[b * 2 + 0]);
  p.qw = cosf(0.5f * theta);
  p.qy = sinf(0.5f * theta);
  float area  = dx * dy;
  p.scale     = expf(ls[b]);
  float depth = sqrtf(expf(ld[b]) / area);
  float cx = mx + t2[b * 2 + 0] * dx;
  float cy = my + t2[b * 2 + 1] * dy;
  float tux = cy, tuy = -cx;
  float n = sqrtf(tux * tux + tuy * tuy + 1.0f);
  p.tx = depth * (tux / n);
  p.ty = depth * (tuy / n);
  p.tz = depth * (-1.0f / n);
  // first-max argmax over 8 class probs (exact compares -> matches np)
  float pmax = cp[b * NC];
  int cls = 0;
  for (int c = 1; c < NC; ++c) {
    float pv = cp[b * NC + c];
    if (pv > pmax) { pmax = pv; cls = c; }
  }
  p.cls  = cls;
  p.feff = 2.0f * focals[b] / (float)NR;
  return p;
}

// ---- kernel 1: all small per-batch outputs ----------------------------------
__global__ void scalars_kernel(const float* __restrict__ roi,
                               const float* __restrict__ focals,
                               const float* __restrict__ td,
                               const float* __restrict__ t2,
                               const float* __restrict__ ls,
                               const float* __restrict__ ld,
                               const float* __restrict__ cp,
                               float* __restrict__ out) {
  int b = threadIdx.x;
  if (b >= NB) return;
  float r0 = roi[b * 4 + 0], r1 = roi[b * 4 + 1];
  float r2 = roi[b * 4 + 2], r3 = roi[b * 4 + 3];
  float dx = r2 - r0, dy = r3 - r1;
  float mx = 0.5f * (r2 + r0), my = 0.5f * (r3 + r1);
  float theta = atan2f(td[b * 2 + 1], td[b * 2 + 0]);
  float qw = cosf(0.5f * theta);
  float qy = sinf(0.5f * theta);
  float area  = dx * dy;
  float scale = expf(ls[b]);
  float depth = sqrtf(expf(ld[b]) / area);
  float cx = mx + t2[b * 2 + 0] * dx;
  float cy = my + t2[b * 2 + 1] * dy;
  float tux = cy, tuy = -cx;
  float n = sqrtf(tux * tux + tuy * tuy + 1.0f);
  float tx_ = depth * (tux / n);
  float ty_ = depth * (tuy / n);
  float tz_ = depth * (-1.0f / n);
  // alphas = -(theta - arctan(tx/tz)), wrapped to [-pi, pi)
  float alpha = -(theta - atanf(tx_ / tz_));
  float a  = alpha + PI_F;
  float rr = fmodf(a, TWOPI_F);
  if (rr < 0.0f) rr += TWOPI_F;
  float alpha_out = rr - PI_F;
  // class log prob
  float pmax = cp[b * NC];
  for (int c = 1; c < NC; ++c) pmax = fmaxf(pmax, cp[b * NC + c]);

  out[OFF_THETAS + b]      = theta;
  out[OFF_ALPHAS + b]      = alpha_out;
  out[OFF_ROT + 4 * b + 0] = qw;
  out[OFF_ROT + 4 * b + 1] = 0.0f;
  out[OFF_ROT + 4 * b + 2] = qy;
  out[OFF_ROT + 4 * b + 3] = 0.0f;
  out[OFF_SCALES + b]      = scale;
  out[OFF_DEPTHS + b]      = depth;
  out[OFF_C2D + 2 * b + 0] = cx;
  out[OFF_C2D + 2 * b + 1] = cy;
  out[OFF_TRANS + 3 * b + 0] = tx_;
  out[OFF_TRANS + 3 * b + 1] = ty_;
  out[OFF_TRANS + 3 * b + 2] = tz_;
  out[OFF_CLP + b]         = logf(pmax);
}

// ---- kernel 2: zero the mask region (harness does not re-poison) ------------
__global__ void fill_kernel(float4* __restrict__ p, int n4) {
  int i = blockIdx.x * blockDim.x + threadIdx.x;
  if (i < n4) {
    float4 z; z.x = 0.0f; z.y = 0.0f; z.z = 0.0f; z.w = 0.0f;
    p[i] = z;
  }
}

// ---- kernel 3: FFD deform + rotate + translate + project + mask scatter -----
__global__ __launch_bounds__(256) void verts_kernel(
    const float* __restrict__ roi, const float* __restrict__ focals,
    const float* __restrict__ td,  const float* __restrict__ t2,
    const float* __restrict__ ls,  const float* __restrict__ ld,
    const float* __restrict__ cp,
    const float* __restrict__ coeffs,   // (B, C, K, 3)
    const float* __restrict__ basev,    // (C, V, 3)
    const float* __restrict__ basis,    // (C, V, K)
    float* __restrict__ out) {
  __shared__ BParams sp;
  __shared__ float scoef[NK * 3];
  int b   = blockIdx.x;            // batch fast -> concurrent blocks share v-tile
  int tid = threadIdx.x;
  if (tid == 0) sp = compute_params(b, roi, focals, td, t2, ls, ld, cp);
  __syncthreads();
  BParams p = sp;
  if (tid < NK * 3) scoef[tid] = coeffs[(b * NC + p.cls) * NK * 3 + tid];
  __syncthreads();

  int v = blockIdx.y * 256 + tid;
  const float4* brow = (const float4*)(basis + (p.cls * NV + v) * NK);
  const float*  bp   = basev + (p.cls * NV + v) * 3;

  float dxv = 0.0f, dyv = 0.0f, dzv = 0.0f;
#pragma unroll
  for (int k4 = 0; k4 < NK / 4; ++k4) {
    float4 bv = brow[k4];
    int k = k4 * 4;
    dxv = fmaf(bv.x, scoef[3 * (k + 0) + 0], dxv);
    dyv = fmaf(bv.x, scoef[3 * (k + 0) + 1], dyv);
    dzv = fmaf(bv.x, scoef[3 * (k + 0) + 2], dzv);
    dxv = fmaf(bv.y, scoef[3 * (k + 1) + 0], dxv);
    dyv = fmaf(bv.y, scoef[3 * (k + 1) + 1], dyv);
    dzv = fmaf(bv.y, scoef[3 * (k + 1) + 2], dzv);
    dxv = fmaf(bv.z, scoef[3 * (k + 2) + 0], dxv);
    dyv = fmaf(bv.z, scoef[3 * (k + 2) + 1], dyv);
    dzv = fmaf(bv.z, scoef[3 * (k + 2) + 2], dzv);
    dxv = fmaf(bv.w, scoef[3 * (k + 3) + 0], dxv);
    dyv = fmaf(bv.w, scoef[3 * (k + 3) + 1], dyv);
    dzv = fmaf(bv.w, scoef[3 * (k + 3) + 2], dzv);
  }

  float vx = (bp[0] + dxv) * p.scale;
  float vy = (bp[1] + dyv) * p.scale;
  float vz = (bp[2] + dzv) * p.scale;
  // quaternion (qw, 0, qy, 0) rotation
  float t2x = 2.0f * p.qy * vz;
  float t2z = -2.0f * p.qy * vx;
  float rx = vx + p.qw * t2x + p.qy * t2z;
  float ry = vy;
  float rz = vz + p.qw * t2z - p.qy * t2x;
  float wx = rx + p.tx, wy = ry + p.ty, wz = rz + p.tz;

  float z = wz;
  float zsafe = (z > -1e-4f) ? -1e-4f : z;
  float inv = p.feff / (-zsafe);
  float u  = wx * inv;
  float vv = wy * inv;
  float px = (u * 0.5f + 0.5f) * (float)NR;
  float py = (vv * 0.5f + 0.5f) * (float)NR;

  float* o = out + OFF_VP + (size_t)(b * NV + v) * 3;
  o[0] = px; o[1] = py; o[2] = -z;

  // clamp-then-trunc == astype(int32)-then-clip for all reachable values
  int xi = (int)fminf(fmaxf(px, 0.0f), 127.0f);
  int yi = (int)fminf(fmaxf(py, 0.0f), 127.0f);
  out[OFF_MASKS + (b << 14) + yi * NR + xi] = 1.0f;
}

extern "C" void kernel_launch(void* const* d_in, const int* in_sizes, int n_in,
                              void* d_out, int out_size, void* d_ws, size_t ws_size,
                              hipStream_t stream) {
  const float* roi    = (const float*)d_in[0];
  const float* focals = (const float*)d_in[1];
  const float* td     = (const float*)d_in[2];
  const float* t2     = (const float*)d_in[3];
  const float* ls     = (const float*)d_in[4];
  const float* ld     = (const float*)d_in[5];
  const float* cp     = (const float*)d_in[6];
  const float* fc     = (const float*)d_in[7];
  const float* bv     = (const float*)d_in[8];
  const float* fb     = (const float*)d_in[9];
  float* out = (float*)d_out;

  scalars_kernel<<<dim3(1), dim3(128), 0, stream>>>(roi, focals, td, t2, ls, ld, cp, out);
  fill_kernel<<<dim3(2048), dim3(256), 0, stream>>>((float4*)(out + OFF_MASKS), 2097152 / 4);
  verts_kernel<<<dim3(NB, NV / 256), dim3(256), 0, stream>>>(
      roi, focals, td, t2, ls, ld, cp, fc, bv, fb, out);
}

// Round 2
// 49.922 us; speedup vs baseline: 1.7993x; 1.7993x over previous
//
#include <hip/hip_runtime.h>
#include <math.h>

#define NB 128
#define NC 8
#define NV 16384
#define NK 64
#define NR 128

// flat output offsets (elements, f32)
#define OFF_MASKS  0
#define OFF_VP     2097152
#define OFF_THETAS 8388608
#define OFF_ALPHAS 8388736
#define OFF_ROT    8388864
#define OFF_SCALES 8389376
#define OFF_DEPTHS 8389504
#define OFF_C2D    8389632
#define OFF_TRANS  8389888
#define OFF_CLP    8390272

#define PI_F     3.14159265358979323846f
#define TWOPI_F  6.28318530717958647692f

// d_ws layout: int cls[128] at byte 0; float params[128][8] at byte 512
// params: [scale, qw, qy, tx, ty, tz, feff, pad]

__device__ __forceinline__ float rflf(float x) {
  return __int_as_float(__builtin_amdgcn_readfirstlane(__float_as_int(x)));
}

// ---- kernel 1: zero masks (grid-wide) + per-batch scalars (block 0) ---------
__global__ __launch_bounds__(256) void prep_kernel(
    const float* __restrict__ roi, const float* __restrict__ focals,
    const float* __restrict__ td,  const float* __restrict__ t2,
    const float* __restrict__ ls,  const float* __restrict__ ld,
    const float* __restrict__ cp,
    float* __restrict__ out, int* __restrict__ wcls, float* __restrict__ wpar) {
  int tid = threadIdx.x;
  // zero-fill mask region: 2,097,152 floats = 524,288 float4 = 2048 blocks * 256
  int i = blockIdx.x * 256 + tid;
  float4 z; z.x = 0.0f; z.y = 0.0f; z.z = 0.0f; z.w = 0.0f;
  ((float4*)(out + OFF_MASKS))[i] = z;

  if (blockIdx.x == 0 && tid < NB) {
    int b = tid;
    float r0 = roi[b * 4 + 0], r1 = roi[b * 4 + 1];
    float r2 = roi[b * 4 + 2], r3 = roi[b * 4 + 3];
    float dx = r2 - r0, dy = r3 - r1;
    float mx = 0.5f * (r2 + r0), my = 0.5f * (r3 + r1);
    float theta = atan2f(td[b * 2 + 1], td[b * 2 + 0]);
    float qw = cosf(0.5f * theta);
    float qy = sinf(0.5f * theta);
    float area  = dx * dy;
    float scale = expf(ls[b]);
    float depth = sqrtf(expf(ld[b]) / area);
    float cx = mx + t2[b * 2 + 0] * dx;
    float cy = my + t2[b * 2 + 1] * dy;
    float tux = cy, tuy = -cx;
    float n = sqrtf(tux * tux + tuy * tuy + 1.0f);
    float tx_ = depth * (tux / n);
    float ty_ = depth * (tuy / n);
    float tz_ = depth * (-1.0f / n);
    float alpha = -(theta - atanf(tx_ / tz_));
    float a  = alpha + PI_F;
    float rr = fmodf(a, TWOPI_F);
    if (rr < 0.0f) rr += TWOPI_F;
    float alpha_out = rr - PI_F;
    // first-max argmax over 8 class probs
    float pmax = cp[b * NC];
    int cls = 0;
    for (int c = 1; c < NC; ++c) {
      float pv = cp[b * NC + c];
      if (pv > pmax) { pmax = pv; cls = c; }
    }
    float feff = 2.0f * focals[b] / (float)NR;

    out[OFF_THETAS + b]      = theta;
    out[OFF_ALPHAS + b]      = alpha_out;
    out[OFF_ROT + 4 * b + 0] = qw;
    out[OFF_ROT + 4 * b + 1] = 0.0f;
    out[OFF_ROT + 4 * b + 2] = qy;
    out[OFF_ROT + 4 * b + 3] = 0.0f;
    out[OFF_SCALES + b]      = scale;
    out[OFF_DEPTHS + b]      = depth;
    out[OFF_C2D + 2 * b + 0] = cx;
    out[OFF_C2D + 2 * b + 1] = cy;
    out[OFF_TRANS + 3 * b + 0] = tx_;
    out[OFF_TRANS + 3 * b + 1] = ty_;
    out[OFF_TRANS + 3 * b + 2] = tz_;
    out[OFF_CLP + b]         = logf(pmax);

    wcls[b] = cls;
    float* p = wpar + b * 8;
    p[0] = scale; p[1] = qw; p[2] = qy; p[3] = tx_;
    p[4] = ty_;   p[5] = tz_; p[6] = feff; p[7] = 0.0f;
  }
}

// ---- kernel 2: class-major FFD + transform + project + scatter --------------
// grid: x = 512 (class = bx&7, vtile = bx>>3), y = 4 (batch split)
// basis row held in VGPRs; coeff/params via wave-uniform (scalar) loads.

#define KSTEP(i) {                                                             \
    float4 c0 = cc[3 * (i) + 0];                                               \
    float4 c1 = cc[3 * (i) + 1];                                               \
    float4 c2 = cc[3 * (i) + 2];                                               \
    float4 bv = bs[(i)];                                                       \
    dxv = fmaf(bv.x, c0.x, dxv); dyv = fmaf(bv.x, c0.y, dyv); dzv = fmaf(bv.x, c0.z, dzv); \
    dxv = fmaf(bv.y, c0.w, dxv); dyv = fmaf(bv.y, c1.x, dyv); dzv = fmaf(bv.y, c1.y, dzv); \
    dxv = fmaf(bv.z, c1.z, dxv); dyv = fmaf(bv.z, c1.w, dyv); dzv = fmaf(bv.z, c2.x, dzv); \
    dxv = fmaf(bv.w, c2.y, dxv); dyv = fmaf(bv.w, c2.z, dyv); dzv = fmaf(bv.w, c2.w, dzv); }

__global__ __launch_bounds__(256, 4) void verts_kernel(
    const float* __restrict__ coeffs,   // (B, C, K, 3)
    const float* __restrict__ basev,    // (C, V, 3)
    const float* __restrict__ basis,    // (C, V, K)
    const int*   __restrict__ wcls,
    const float* __restrict__ wpar,
    float* __restrict__ out) {
  int bx   = blockIdx.x;
  int myc  = bx & 7;          // class
  int tile = bx >> 3;         // vertex tile
  int v    = tile * 256 + threadIdx.x;

  const float4* brow = (const float4*)(basis + ((size_t)myc * NV + v) * NK);
  float4 bs[16];
  bs[0]  = brow[0];  bs[1]  = brow[1];  bs[2]  = brow[2];  bs[3]  = brow[3];
  bs[4]  = brow[4];  bs[5]  = brow[5];  bs[6]  = brow[6];  bs[7]  = brow[7];
  bs[8]  = brow[8];  bs[9]  = brow[9];  bs[10] = brow[10]; bs[11] = brow[11];
  bs[12] = brow[12]; bs[13] = brow[13]; bs[14] = brow[14]; bs[15] = brow[15];
  const float* bp = basev + ((size_t)myc * NV + v) * 3;
  float bpx = bp[0], bpy = bp[1], bpz = bp[2];

  for (int b = blockIdx.y; b < NB; b += 4) {
    int cls = __builtin_amdgcn_readfirstlane(wcls[b]);
    if (cls != myc) continue;

    const float4* cc = (const float4*)(coeffs + ((size_t)(b * NC + myc)) * NK * 3);
    float dxv = 0.0f, dyv = 0.0f, dzv = 0.0f;
    KSTEP(0)  KSTEP(1)  KSTEP(2)  KSTEP(3)
    KSTEP(4)  KSTEP(5)  KSTEP(6)  KSTEP(7)
    KSTEP(8)  KSTEP(9)  KSTEP(10) KSTEP(11)
    KSTEP(12) KSTEP(13) KSTEP(14) KSTEP(15)

    const float* pp = wpar + b * 8;
    float scale = rflf(pp[0]);
    float qw    = rflf(pp[1]);
    float qy    = rflf(pp[2]);
    float tx    = rflf(pp[3]);
    float ty    = rflf(pp[4]);
    float tz    = rflf(pp[5]);
    float feff  = rflf(pp[6]);

    float vx = (bpx + dxv) * scale;
    float vy = (bpy + dyv) * scale;
    float vz = (bpz + dzv) * scale;
    // quaternion (qw, 0, qy, 0) rotation
    float t2x = 2.0f * qy * vz;
    float t2z = -2.0f * qy * vx;
    float rx = vx + qw * t2x + qy * t2z;
    float ry = vy;
    float rz = vz + qw * t2z - qy * t2x;
    float wx = rx + tx, wy = ry + ty, wz = rz + tz;

    float zv = wz;
    float zsafe = (zv > -1e-4f) ? -1e-4f : zv;
    float inv = feff / (-zsafe);
    float u  = wx * inv;
    float vv = wy * inv;
    float px = (u * 0.5f + 0.5f) * (float)NR;
    float py = (vv * 0.5f + 0.5f) * (float)NR;

    float* o = out + OFF_VP + (size_t)(b * NV + v) * 3;
    o[0] = px; o[1] = py; o[2] = -zv;

    int xi = (int)fminf(fmaxf(px, 0.0f), 127.0f);
    int yi = (int)fminf(fmaxf(py, 0.0f), 127.0f);
    out[OFF_MASKS + (b << 14) + yi * NR + xi] = 1.0f;
  }
}

extern "C" void kernel_launch(void* const* d_in, const int* in_sizes, int n_in,
                              void* d_out, int out_size, void* d_ws, size_t ws_size,
                              hipStream_t stream) {
  const float* roi    = (const float*)d_in[0];
  const float* focals = (const float*)d_in[1];
  const float* td     = (const float*)d_in[2];
  const float* t2     = (const float*)d_in[3];
  const float* ls     = (const float*)d_in[4];
  const float* ld     = (const float*)d_in[5];
  const float* cp     = (const float*)d_in[6];
  const float* fc     = (const float*)d_in[7];
  const float* bv     = (const float*)d_in[8];
  const float* fb     = (const float*)d_in[9];
  float* out = (float*)d_out;
  int*   wcls = (int*)d_ws;
  float* wpar = (float*)d_ws + 128;

  prep_kernel<<<dim3(2048), dim3(256), 0, stream>>>(
      roi, focals, td, t2, ls, ld, cp, out, wcls, wpar);
  verts_kernel<<<dim3(512, 4), dim3(256), 0, stream>>>(
      fc, bv, fb, wcls, wpar, out);
}